// Round 10
// baseline (948.903 us; speedup 1.0000x reference)
//
#include <hip/hip_runtime.h>
#include <math.h>

#define N_NODES 10000
#define NPAD    10016          // mult of 4; padded key-row length
#define L_LEN   256
#define D_DIM   32
#define K_NBR   32
#define NTOT    (N_NODES * L_LEN)
#define EPS_BN  1e-5f
#define QB      3              // queries per block in knn3
#define BT      1024           // threads per block in knn3
#define SD      3              // float4 stripes: 3*1024*4 = 12288 >= NPAD

typedef unsigned int uint4_ev __attribute__((ext_vector_type(4)));

__device__ __forceinline__ float silu_f(float x) {
    return x / (1.0f + expf(-x));
}

// ---------- kernel 1: global sum & sumsq of pop ----------
__global__ void stats_kernel(const float* __restrict__ pop, float* __restrict__ stats) {
    __shared__ float s1[256], s2[256];
    int t = threadIdx.x;
    float a = 0.f, b = 0.f;
    for (int idx = blockIdx.x * 256 + t; idx < NTOT; idx += gridDim.x * 256) {
        float v = pop[idx];
        a += v; b += v * v;
    }
    s1[t] = a; s2[t] = b;
    __syncthreads();
    for (int s = 128; s > 0; s >>= 1) {
        if (t < s) { s1[t] += s1[t + s]; s2[t] += s2[t + s]; }
        __syncthreads();
    }
    if (t == 0) { atomicAdd(&stats[0], s1[0]); atomicAdd(&stats[1], s2[0]); }
}

// ---------- kernel 2: featurize (BN folded to global scalar stats) ----------
__global__ void feat_kernel(const float* __restrict__ pop,
                            const float* __restrict__ conv_w,
                            const float* __restrict__ conv_b,
                            const float* __restrict__ gamma,
                            const float* __restrict__ beta,
                            const float* __restrict__ stats,
                            float* __restrict__ X,
                            float* __restrict__ XT,
                            float* __restrict__ SQ) {
    __shared__ float row[L_LEN];
    __shared__ float part[256];
    int i = blockIdx.x;
    int t = threadIdx.x;
    row[t] = pop[i * L_LEN + t];
    __syncthreads();
    int d = t & 31, g = t >> 5;
    float M  = stats[0] * (1.0f / NTOT);
    float Vc = stats[1] * (1.0f / NTOT) - M * M;
    float w = conv_w[d], b = conv_b[d];
    float mean = fmaf(w, M, b);
    float var  = w * w * Vc;
    float sc = gamma[d] / sqrtf(var + EPS_BN);
    float bt = beta[d];
    float acc = 0.f;
    int l0 = g * 32;
    #pragma unroll
    for (int l = 0; l < 32; ++l) {
        float y = fmaf(row[l0 + l], w, b);
        float z = fmaf(y - mean, sc, bt);
        acc += silu_f(z);
    }
    part[t] = acc;
    __syncthreads();
    if (t < 32) {
        float s = 0.f;
        #pragma unroll
        for (int gg = 0; gg < 8; ++gg) s += part[gg * 32 + t];
        float xv = s * (1.0f / L_LEN);
        X[i * D_DIM + t] = xv;
        XT[t * N_NODES + i] = xv;
        part[t] = xv;
    }
    __syncthreads();
    if (t == 0) {
        float sq = 0.f;
        #pragma unroll
        for (int dd = 0; dd < 32; ++dd) sq += part[dd] * part[dd];
        SQ[i] = sq;
    }
}

// ---------- kernel 3: fused multi-query kNN ----------
// QB=3 queries/block share each XT read. Select: 3 queries processed
// CONCURRENTLY by wave-groups {0-4},{5-9},{10-15}; per-wave private 256-bin
// histograms kill atomic contention; 4 uniform rounds; tie phase is one wave
// per group (no barriers). Exact top-k, lowest-index ties (top_k semantics).
__global__ __launch_bounds__(BT) void knn3_kernel(const float* __restrict__ X,
                                                  const float* __restrict__ XT,
                                                  const float* __restrict__ SQ,
                                                  int* __restrict__ NBR) {
    extern __shared__ unsigned int keys[];      // [QB][NPAD]
    __shared__ float qv[QB][D_DIM];
    __shared__ float sqq[QB];
    __shared__ unsigned int whist[16][256];     // per-wave private hist (16 KB)
    __shared__ unsigned int wmin[16], wmax[16];
    __shared__ unsigned int gkmin[QB], gkmax[QB], gkth[QB];
    __shared__ int gwant[QB], gcnt[QB];

    int t = threadIdx.x;
    int lane = t & 63;
    int w = t >> 6;                             // wave id 0..15
    int q0 = blockIdx.x * QB;

    if (t < QB * D_DIM) {
        int q = t >> 5, d = t & 31;
        int gq_ = q0 + q;
        qv[q][d] = (gq_ < N_NODES) ? X[gq_ * D_DIM + d] : 0.f;
    }
    if (t < QB) sqq[t] = (q0 + t < N_NODES) ? SQ[q0 + t] : 0.f;
    __syncthreads();

    // ---- distance phase: d-outer, j-inner (float4), acc[q][stripe*4+jj] ----
    float acc[QB][SD * 4];
    #pragma unroll
    for (int q = 0; q < QB; ++q)
        #pragma unroll
        for (int s = 0; s < SD * 4; ++s) acc[q][s] = 0.f;

    #pragma unroll 2
    for (int d = 0; d < D_DIM; ++d) {
        float qd0 = qv[0][d], qd1 = qv[1][d], qd2 = qv[2][d];
        const float4* xr4 = (const float4*)(XT + d * N_NODES);
        #pragma unroll
        for (int s = 0; s < SD; ++s) {
            int i4 = t + s * BT;
            float4 xv = make_float4(0.f, 0.f, 0.f, 0.f);
            if (i4 < N_NODES / 4) xv = xr4[i4];
            acc[0][s * 4 + 0] = fmaf(qd0, xv.x, acc[0][s * 4 + 0]);
            acc[0][s * 4 + 1] = fmaf(qd0, xv.y, acc[0][s * 4 + 1]);
            acc[0][s * 4 + 2] = fmaf(qd0, xv.z, acc[0][s * 4 + 2]);
            acc[0][s * 4 + 3] = fmaf(qd0, xv.w, acc[0][s * 4 + 3]);
            acc[1][s * 4 + 0] = fmaf(qd1, xv.x, acc[1][s * 4 + 0]);
            acc[1][s * 4 + 1] = fmaf(qd1, xv.y, acc[1][s * 4 + 1]);
            acc[1][s * 4 + 2] = fmaf(qd1, xv.z, acc[1][s * 4 + 2]);
            acc[1][s * 4 + 3] = fmaf(qd1, xv.w, acc[1][s * 4 + 3]);
            acc[2][s * 4 + 0] = fmaf(qd2, xv.x, acc[2][s * 4 + 0]);
            acc[2][s * 4 + 1] = fmaf(qd2, xv.y, acc[2][s * 4 + 1]);
            acc[2][s * 4 + 2] = fmaf(qd2, xv.z, acc[2][s * 4 + 2]);
            acc[2][s * 4 + 3] = fmaf(qd2, xv.w, acc[2][s * 4 + 3]);
        }
    }

    // ---- key phase: d2 -> order-preserving u32 keys in LDS ----
    const float4* sq4p = (const float4*)SQ;
    #pragma unroll
    for (int s = 0; s < SD; ++s) {
        int i4 = t + s * BT;
        int j4 = 4 * i4;
        if (j4 < NPAD) {
            float4 sj = make_float4(0.f, 0.f, 0.f, 0.f);
            if (i4 < N_NODES / 4) sj = sq4p[i4];
            float sjv[4] = { sj.x, sj.y, sj.z, sj.w };
            #pragma unroll
            for (int q = 0; q < QB; ++q) {
                int gq_ = q0 + q;
                unsigned int kk[4];
                #pragma unroll
                for (int jj = 0; jj < 4; ++jj) {
                    int j = j4 + jj;
                    unsigned int kv = 0xFFFFFFFFu;
                    if (j < N_NODES && gq_ < N_NODES && j != gq_) {
                        float d2 = (sqq[q] + sjv[jj]) - 2.0f * acc[q][s * 4 + jj];
                        unsigned int u = __float_as_uint(d2);
                        u ^= (u & 0x80000000u) ? 0xFFFFFFFFu : 0x80000000u;
                        kv = u;
                    }
                    kk[jj] = kv;
                }
                uint4_ev wv = { kk[0], kk[1], kk[2], kk[3] };
                *(uint4_ev*)&keys[q * NPAD + j4] = wv;
            }
        }
    }
    __syncthreads();

    // ---- group setup: waves 0-4 -> q0, 5-9 -> q1, 10-15 -> q2 ----
    int g     = (w >= 10) ? 2 : (w >= 5 ? 1 : 0);
    int wbase = (g == 2) ? 10 : g * 5;
    int gsz   = (g == 2) ? 6 : 5;
    int lt    = (w - wbase) * 64 + lane;        // local thread in group
    int GT    = gsz * 64;                       // group thread count
    unsigned int* kq = keys + g * NPAD;
    int gq = q0 + g;

    // ---- range phase: per-group key min/max (max excludes sentinels) ----
    unsigned int mn = 0xFFFFFFFFu, mx = 0u;
    for (int j = lt; j < NPAD; j += GT) {
        unsigned int u = kq[j];
        mn = mn < u ? mn : u;
        if (u != 0xFFFFFFFFu) mx = mx > u ? mx : u;
    }
    #pragma unroll
    for (int off = 32; off > 0; off >>= 1) {
        unsigned int a = (unsigned int)__shfl_xor((int)mn, off);
        unsigned int b = (unsigned int)__shfl_xor((int)mx, off);
        mn = mn < a ? mn : a;
        mx = mx > b ? mx : b;
    }
    if (lane == 0) { wmin[w] = mn; wmax[w] = mx; }
    __syncthreads();
    if (t < QB) {
        int b0 = (t == 2) ? 10 : t * 5;
        int bs = (t == 2) ? 6 : 5;
        unsigned int m0 = 0xFFFFFFFFu, m1 = 0u;
        for (int k = 0; k < bs; ++k) {
            m0 = m0 < wmin[b0 + k] ? m0 : wmin[b0 + k];
            m1 = m1 > wmax[b0 + k] ? m1 : wmax[b0 + k];
        }
        gkmin[t] = m0; gkmax[t] = m1;
        gkth[t] = m0; gwant[t] = K_NBR; gcnt[t] = 0;
    }
    __syncthreads();

    // ---- 4 uniform radix rounds (8-bit digits), per-wave hist ----
    for (int shift = 24; shift >= 0; shift -= 8) {
        unsigned int gdiff = gkmin[g] ^ gkmax[g];
        bool skip = (gdiff >> shift) == 0;      // all bits >= shift common
        if (!skip) {
            #pragma unroll
            for (int b = lane; b < 256; b += 64) whist[w][b] = 0u;
            unsigned int kth = gkth[g];
            int sh8 = shift + 8;
            for (int j = lt; j < NPAD; j += GT) {
                unsigned int u = kq[j];
                if (((unsigned long long)u >> sh8) == ((unsigned long long)kth >> sh8))
                    atomicAdd(&whist[w][(u >> shift) & 255u], 1u);
            }
        }
        __syncthreads();
        if (!skip && w == wbase) {              // first wave of group selects
            int want = gwant[g];
            unsigned int kth = gkth[g];
            unsigned int c[4]; unsigned int gsum = 0u;
            #pragma unroll
            for (int i = 0; i < 4; ++i) {
                unsigned int tot = 0u; int b = 4 * lane + i;
                for (int k = 0; k < gsz; ++k) tot += whist[wbase + k][b];
                c[i] = tot; gsum += tot;
            }
            unsigned int x = gsum;
            #pragma unroll
            for (int off = 1; off < 64; off <<= 1) {
                unsigned int y = (unsigned int)__shfl_up((int)x, off);
                if (lane >= off) x += y;
            }
            unsigned int e = x - gsum;
            #pragma unroll
            for (int i = 0; i < 4; ++i) {
                if (e < (unsigned int)want && (unsigned int)want <= e + c[i]) {
                    gwant[g] = want - (int)e;
                    gkth[g] = (kth & ~(255u << shift)) |
                              ((unsigned int)(4 * lane + i) << shift);
                }
                e += c[i];
            }
        }
        __syncthreads();
    }

    // ---- collect phase (no more barriers needed) ----
    unsigned int kth = gkth[g];
    int wantEq = gwant[g];
    int baseSlot = K_NBR - wantEq;              // = count strictly-less
    if (gq < N_NODES) {
        for (int j = lt; j < NPAD; j += GT) {
            if (kq[j] < kth) {
                int p = atomicAdd(&gcnt[g], 1);
                NBR[gq * K_NBR + p] = j;
            }
        }
        if (w == wbase) {                       // tie phase: one wave, in-wave only
            int last = -1;
            for (int e = 0; e < wantEq; ++e) {
                unsigned int best = 0xFFFFFFFFu;
                for (int j = lane; j < NPAD; j += 64) {
                    if (kq[j] == kth && j > last && (unsigned int)j < best)
                        best = (unsigned int)j;
                }
                #pragma unroll
                for (int off = 32; off > 0; off >>= 1) {
                    unsigned int o = (unsigned int)__shfl_xor((int)best, off);
                    best = best < o ? best : o;
                }
                if (lane == 0) NBR[gq * K_NBR + baseSlot + e] = (int)best;
                last = (int)best;
            }
        }
    }
}

// ---------- kernel 4: fused GCN layer ----------
// By linearity: silu( ((x_i + sum_nbr x_j)/33) @ W + b ). One kernel per layer.
__global__ void gcn_fused(const float* __restrict__ Xin, const int* __restrict__ NBR,
                          const float* __restrict__ W, const float* __restrict__ bias,
                          float* __restrict__ Xout) {
    __shared__ float Ws[D_DIM * D_DIM];
    __shared__ float sAgg[8][D_DIM];
    __shared__ int nb[8][K_NBR];
    int t = threadIdx.x, g = t >> 5, d = t & 31;
    #pragma unroll
    for (int q = 0; q < 4; ++q) Ws[q * 256 + t] = W[q * 256 + t];
    int i = blockIdx.x * 8 + g;
    nb[g][d] = NBR[i * K_NBR + d];
    __syncthreads();
    float s = Xin[i * D_DIM + d];
    #pragma unroll 8
    for (int e = 0; e < K_NBR; ++e) s += Xin[nb[g][e] * D_DIM + d];
    sAgg[g][d] = s;
    __syncthreads();
    float acc = 0.f;
    #pragma unroll
    for (int m = 0; m < D_DIM; ++m)
        acc = fmaf(sAgg[g][m], Ws[m * D_DIM + d], acc);
    float v = fmaf(acc, 1.0f / 33.0f, bias[d]);   // deg == 33 for every node
    Xout[i * D_DIM + d] = silu_f(v);
}

// ---------- kernel 5: fused out-proj + aggregate + softmax ----------
__global__ void out_final(const float* __restrict__ Xin, const int* __restrict__ NBR,
                          const float* __restrict__ Wout, const float* __restrict__ out_b,
                          float* __restrict__ out) {
    __shared__ float Ws[D_DIM * 3];
    __shared__ float sAgg[8][D_DIM];
    __shared__ int nb[8][K_NBR];
    int t = threadIdx.x, g = t >> 5, d = t & 31;
    if (t < D_DIM * 3) Ws[t] = Wout[t];
    int i = blockIdx.x * 8 + g;
    nb[g][d] = NBR[i * K_NBR + d];
    __syncthreads();
    float s = Xin[i * D_DIM + d];
    #pragma unroll 8
    for (int e = 0; e < K_NBR; ++e) s += Xin[nb[g][e] * D_DIM + d];
    sAgg[g][d] = s;
    __syncthreads();
    if (d < 3) {
        float v[3];
        #pragma unroll
        for (int c = 0; c < 3; ++c) {
            float a = 0.f;
            #pragma unroll
            for (int m = 0; m < D_DIM; ++m) a = fmaf(sAgg[g][m], Ws[m * 3 + c], a);
            v[c] = fmaf(a, 1.0f / 33.0f, out_b[c]);
        }
        float mx = fmaxf(v[0], fmaxf(v[1], v[2]));
        float e0 = expf(v[0] - mx), e1 = expf(v[1] - mx), e2 = expf(v[2] - mx);
        out[i * 3 + d] = expf(v[d] - mx) / (e0 + e1 + e2);
    }
}

extern "C" void kernel_launch(void* const* d_in, const int* in_sizes, int n_in,
                              void* d_out, int out_size, void* d_ws, size_t ws_size,
                              hipStream_t stream) {
    const float* pop    = (const float*)d_in[0];
    const float* conv_w = (const float*)d_in[1];
    const float* conv_b = (const float*)d_in[2];
    const float* gamma  = (const float*)d_in[3];
    const float* beta   = (const float*)d_in[4];
    const float* gcn_ws = (const float*)d_in[5];
    const float* gcn_bs = (const float*)d_in[6];
    const float* out_w  = (const float*)d_in[7];
    const float* out_b  = (const float*)d_in[8];

    char* ws = (char*)d_ws;
    const size_t o_stats = 0;
    const size_t o_X     = 256;
    const size_t o_XT    = o_X + 1280000;
    const size_t o_SQ    = o_XT + 1280000;
    const size_t o_H     = o_SQ + 40192;
    const size_t o_NBR   = o_H + 1280000;

    float* stats = (float*)(ws + o_stats);
    float* X     = (float*)(ws + o_X);
    float* XT    = (float*)(ws + o_XT);
    float* SQ    = (float*)(ws + o_SQ);
    float* H     = (float*)(ws + o_H);
    int*   NBR   = (int*)  (ws + o_NBR);
    float* out   = (float*)d_out;

    (void)hipMemsetAsync(stats, 0, 2 * sizeof(float), stream);
    stats_kernel<<<512, 256, 0, stream>>>(pop, stats);
    feat_kernel<<<N_NODES, 256, 0, stream>>>(pop, conv_w, conv_b, gamma, beta, stats, X, XT, SQ);

    const int nqb = (N_NODES + QB - 1) / QB;                 // 3334
    const size_t keys_bytes = (size_t)QB * NPAD * 4;         // 120192 B dynamic LDS
    knn3_kernel<<<nqb, BT, keys_bytes, stream>>>(X, XT, SQ, NBR);

    gcn_fused<<<N_NODES / 8, 256, 0, stream>>>(X, NBR, gcn_ws,        gcn_bs,      H);
    gcn_fused<<<N_NODES / 8, 256, 0, stream>>>(H, NBR, gcn_ws + 1024, gcn_bs + 32, X);
    gcn_fused<<<N_NODES / 8, 256, 0, stream>>>(X, NBR, gcn_ws + 2048, gcn_bs + 64, H);
    out_final<<<N_NODES / 8, 256, 0, stream>>>(H, NBR, out_w, out_b, out);
}